// Round 5
// baseline (233.685 us; speedup 1.0000x reference)
//
#include <hip/hip_runtime.h>

#define RADIUS 2
#define TH 4                 // output rows per thread (best traffic point: 2x vert amplification)
#define LOG2E 1.4426950408889634f
#define NEG50L (-50.0f * LOG2E)   // -0.5 * (1/sigma_color^2) * log2(e)

// compile-time problem shape (bench is fixed at 16x512x512x3 f32 NHWC)
#define B_ 16
#define H_ 512
#define W_ 512
#define TILES (H_ / TH)      // 128
#define RS (W_ * 3)          // row stride in floats

#define EXP2(x) __builtin_amdgcn_exp2f(x)

// 16B vector load with only 4B alignment guarantee (row base is 12B-aligned).
typedef float f4 __attribute__((ext_vector_type(4), aligned(4)));

__device__ __forceinline__ void load15(float d[15], const float* __restrict__ p) {
    f4 a = *(const f4*)(p + 0);
    f4 b = *(const f4*)(p + 4);
    f4 c = *(const f4*)(p + 8);
    f4 e = *(const f4*)(p + 11);      // overlaps c.w; keeps it 4 VMEM instrs
    d[0] = a.x;  d[1] = a.y;  d[2]  = a.z;  d[3]  = a.w;
    d[4] = b.x;  d[5] = b.y;  d[6]  = b.z;  d[7]  = b.w;
    d[8] = c.x;  d[9] = c.y;  d[10] = c.z;  d[11] = e.x;
    d[12] = e.y; d[13] = e.z; d[14] = e.w;
}

// 5 taps of one window row (dy is unroll-constant) for one center pixel.
// Center tap (dy==2,dx==2) is pre-folded into the accumulator init.
__device__ __forceinline__ void taps_row(const float row[15], int dy,
                                         float cr, float cg, float cb,
                                         float& ar, float& ag, float& ab,
                                         float& ad) {
    const int sdy = (dy - 2) * (dy - 2);
#pragma unroll
    for (int dx = 0; dx < 5; ++dx) {
        if (dy == 2 && dx == 2) continue;   // folds away
        const float nr = row[3 * dx + 0];
        const float ng = row[3 * dx + 1];
        const float nb = row[3 * dx + 2];
        const float dr = nr - cr, dg = ng - cg, db = nb - cb;
        float cd = dr * dr;
        cd = fmaf(dg, dg, cd);
        cd = fmaf(db, db, cd);
        const float spatial =
            -0.5f * LOG2E * (float)(sdy + (dx - 2) * (dx - 2));
        const float w = EXP2(fmaf(cd, NEG50L, spatial));
        ar = fmaf(w, nr, ar);
        ag = fmaf(w, ng, ag);
        ab = fmaf(w, nb, ab);
        ad += w;
    }
}

// One thread = (batch, column, 4-row tile). Streams 8 input rows; one
// 15-float row live at a time. Live set ~55 floats -> genuinely fits the
// 64-VGPR / 8-wave tier; launch_bounds(256,8) forces the allocator there
// (unconstrained, round-2 compiled this to 76 VGPR / 6-wave tier by
// hoisting loads; 8 waves of TLP beat that ILP at identical traffic).
__global__ __launch_bounds__(256, 8) void bilateral_kernel(
    const float* __restrict__ x, float* __restrict__ out)
{
    const int tid = blockIdx.x * blockDim.x + threadIdx.x;
    const int wslot = tid & (W_ - 1);
    // rotate columns by +RADIUS: edge columns {0,1,510,511} all land in the
    // last 64-lane wave of each 512-column group -> 7 of 8 column-waves are
    // unguarded fast path.
    const int w0 = (wslot + RADIUS) & (W_ - 1);
    const int t  = (tid >> 9) & (TILES - 1);
    const int b0 = tid >> 16;
    const int h0 = t * TH;

    const float* __restrict__ img = x + (size_t)b0 * (H_ * W_ * 3);
    float* __restrict__ oimg      = out + (size_t)b0 * (H_ * W_ * 3);

    // centers: always in-bounds (rows h0..h0+3, column w0)
    float cc[TH][3];
#pragma unroll
    for (int j = 0; j < TH; ++j) {
        const float* cp = img + ((h0 + j) * W_ + w0) * 3;
        cc[j][0] = cp[0]; cc[j][1] = cp[1]; cc[j][2] = cp[2];
    }
    // accumulators, center tap (w==1) pre-folded
    float acc[TH][4];
#pragma unroll
    for (int j = 0; j < TH; ++j) {
        acc[j][0] = cc[j][0];
        acc[j][1] = cc[j][1];
        acc[j][2] = cc[j][2];
        acc[j][3] = 1.0f;
    }

    const bool fast = (t >= 1) && (t <= TILES - 2) &&
                      (w0 >= RADIUS) && (w0 < W_ - RADIUS);

    if (__all(fast)) {
        // interior: unconditional vector row loads
        const float* p = img + ((h0 - 2) * W_ + (w0 - RADIUS)) * 3;
#pragma unroll
        for (int r = 0; r < TH + 4; ++r) {
            float row[15];
            load15(row, p);
            p += RS;
#pragma unroll
            for (int j = 0; j < TH; ++j) {
                if (r - j >= 0 && r - j <= 4)   // unroll-const condition
                    taps_row(row, r - j, cc[j][0], cc[j][1], cc[j][2],
                             acc[j][0], acc[j][1], acc[j][2], acc[j][3]);
            }
        }
    } else {
        // boundary (~14% of waves): per-element guarded loads; OOB taps use
        // nbr=0 but still contribute weight to den (skimage constant mode).
        bool cok[5];
#pragma unroll
        for (int jj = 0; jj < 5; ++jj) {
            const int ww = w0 - RADIUS + jj;
            cok[jj] = (ww >= 0) && (ww < W_);
        }
#pragma unroll
        for (int r = 0; r < TH + 4; ++r) {
            const int hh = h0 - 2 + r;
            const bool rowok = (hh >= 0) && (hh < H_);
            const int base = (hh * W_ + (w0 - RADIUS)) * 3;
            float row[15];
#pragma unroll
            for (int jj = 0; jj < 5; ++jj) {
                const bool ok = rowok && cok[jj];
#pragma unroll
                for (int c = 0; c < 3; ++c)
                    row[3 * jj + c] = ok ? img[base + 3 * jj + c] : 0.0f;
            }
#pragma unroll
            for (int j = 0; j < TH; ++j) {
                if (r - j >= 0 && r - j <= 4)
                    taps_row(row, r - j, cc[j][0], cc[j][1], cc[j][2],
                             acc[j][0], acc[j][1], acc[j][2], acc[j][3]);
            }
        }
    }

#pragma unroll
    for (int j = 0; j < TH; ++j) {
        const float inv = __builtin_amdgcn_rcpf(acc[j][3]);   // den >= 1
        float* op = oimg + ((h0 + j) * W_ + w0) * 3;
        op[0] = acc[j][0] * inv;
        op[1] = acc[j][1] * inv;
        op[2] = acc[j][2] * inv;
    }
}

extern "C" void kernel_launch(void* const* d_in, const int* in_sizes, int n_in,
                              void* d_out, int out_size, void* d_ws, size_t ws_size,
                              hipStream_t stream) {
    const float* x = (const float*)d_in[0];
    float* out = (float*)d_out;

    const int total = B_ * W_ * TILES;      // 1,048,576 (exact multiple of 256)
    const int block = 256;
    const int grid = total / block;

    bilateral_kernel<<<grid, block, 0, stream>>>(x, out);
}

// Round 6
// 56.718 us; speedup vs baseline: 4.1201x; 4.1201x over previous
//
#include <hip/hip_runtime.h>

#define LOG2E 1.4426950408889634f
#define NEG50L (-50.0f * LOG2E)   // -0.5/sigma_color^2 * log2(e)

// compile-time problem shape (bench fixed at 16x512x512x3 f32 NHWC)
#define B_ 16
#define H_ 512
#define W_ 512

#define TILE_C 64            // columns per block (one lane each)
#define TH 4                 // output rows per thread
#define TILE_R 16            // output rows per block (4 waves x TH)
#define LR (TILE_R + 4)      // 20 LDS rows  (halo'd)
#define LC (TILE_C + 4)      // 68 LDS cols  (halo'd)
#define NTEX (LR * LC)       // 1360 texels

#define EXP2(x) __builtin_amdgcn_exp2f(x)

typedef float f4 __attribute__((ext_vector_type(4)));   // 16B-aligned RGBX texel

// One block = 64x16 output tile. Input halo tile staged once into LDS as
// 16B RGBX texels (zero-padded OOB -> no boundary path in the main loop).
// Main loop: ds_read_b128 at lane-stride 16B (dense, conflict-free) replaces
// all global loads -> ~60-cyc LDS latency instead of 200-600-cyc L1/L2,
// which is what the 44% VALU-idle has been waiting on since round 2.
__global__ __launch_bounds__(256) void bilateral_kernel(
    const float* __restrict__ x, float* __restrict__ out)
{
    __shared__ f4 tile[NTEX];          // 21,760 B

    const int bid = blockIdx.x;
    const int ct = bid & 7;            // 8 col tiles
    const int rt = (bid >> 3) & 31;    // 32 row tiles
    const int b0 = bid >> 8;           // 16 batches
    const int c0 = ct * TILE_C;
    const int h0 = rt * TILE_R;

    const float* __restrict__ img = x + (size_t)b0 * (H_ * W_ * 3);
    float* __restrict__ oimg      = out + (size_t)b0 * (H_ * W_ * 3);

    // ---- stage 20x68 RGBX texels (coalesced-ish scalar loads, guarded) ----
    for (int s = threadIdx.x; s < NTEX; s += 256) {
        const int lr = s / LC;                 // magic-mul division
        const int lc = s - lr * LC;
        const int gr = h0 - 2 + lr;
        const int gc = c0 - 2 + lc;
        const bool ok = (gr >= 0) && (gr < H_) && (gc >= 0) && (gc < W_);
        const int gidx = (gr * W_ + gc) * 3;
        f4 t;
        t.x = ok ? img[gidx + 0] : 0.0f;
        t.y = ok ? img[gidx + 1] : 0.0f;
        t.z = ok ? img[gidx + 2] : 0.0f;
        t.w = 0.0f;
        tile[s] = t;                           // ds_write_b128, dense
    }
    __syncthreads();

    const int lane  = threadIdx.x & 63;        // column within tile
    const int wv    = threadIdx.x >> 6;        // wave -> 4-row group
    const int rbase = wv * TH;                 // first LDS row of my stream

    // centers: LDS row rbase+j+2, col lane+2 (always valid tile interior)
    f4 cc[TH];
#pragma unroll
    for (int j = 0; j < TH; ++j)
        cc[j] = tile[(rbase + j + 2) * LC + (lane + 2)];

    // accumulators; center tap (w==1) pre-folded
    float acc[TH][4];
#pragma unroll
    for (int j = 0; j < TH; ++j) {
        acc[j][0] = cc[j].x;
        acc[j][1] = cc[j].y;
        acc[j][2] = cc[j].z;
        acc[j][3] = 1.0f;
    }

    // ---- stream 8 LDS rows; each serves the windows of up to 4 centers ----
#pragma unroll
    for (int r = 0; r < TH + 4; ++r) {
        f4 row[5];
#pragma unroll
        for (int dx = 0; dx < 5; ++dx)
            row[dx] = tile[(rbase + r) * LC + (lane + dx)];   // ds_read_b128

#pragma unroll
        for (int j = 0; j < TH; ++j) {
            if (r - j >= 0 && r - j <= 4) {        // unroll-const
                const int dy = r - j;
                const int sdy = (dy - 2) * (dy - 2);
                const float cr = cc[j].x, cg = cc[j].y, cb = cc[j].z;
#pragma unroll
                for (int dx = 0; dx < 5; ++dx) {
                    if (dy == 2 && dx == 2) continue;   // pre-folded center
                    const float nr = row[dx].x;
                    const float ng = row[dx].y;
                    const float nb = row[dx].z;
                    const float dr = nr - cr, dg = ng - cg, db = nb - cb;
                    float cd = dr * dr;
                    cd = fmaf(dg, dg, cd);
                    cd = fmaf(db, db, cd);
                    const float spatial =
                        -0.5f * LOG2E * (float)(sdy + (dx - 2) * (dx - 2));
                    const float w = EXP2(fmaf(cd, NEG50L, spatial));
                    acc[j][0] = fmaf(w, nr, acc[j][0]);
                    acc[j][1] = fmaf(w, ng, acc[j][1]);
                    acc[j][2] = fmaf(w, nb, acc[j][2]);
                    acc[j][3] += w;
                }
            }
        }
    }

    // ---- epilogue: all outputs in-bounds by construction ----
#pragma unroll
    for (int j = 0; j < TH; ++j) {
        const float inv = __builtin_amdgcn_rcpf(acc[j][3]);   // den >= 1
        float* op = oimg + ((size_t)(h0 + rbase + j) * W_ + (c0 + lane)) * 3;
        op[0] = acc[j][0] * inv;
        op[1] = acc[j][1] * inv;
        op[2] = acc[j][2] * inv;
    }
}

extern "C" void kernel_launch(void* const* d_in, const int* in_sizes, int n_in,
                              void* d_out, int out_size, void* d_ws, size_t ws_size,
                              hipStream_t stream) {
    const float* x = (const float*)d_in[0];
    float* out = (float*)d_out;

    const int grid = B_ * (W_ / TILE_C) * (H_ / TILE_R);   // 16*8*32 = 4096
    const int block = 256;

    bilateral_kernel<<<grid, block, 0, stream>>>(x, out);
}

// Round 7
// 55.833 us; speedup vs baseline: 4.1855x; 1.0159x over previous
//
#include <hip/hip_runtime.h>

#define RADIUS 2
#define TH 4                 // output rows per thread (best traffic/VGPR point)
#define LOG2E 1.4426950408889634f
#define NEG50L (-50.0f * LOG2E)   // -0.5/sigma_color^2 * log2(e)

// compile-time problem shape (bench fixed at 16x512x512x3 f32 NHWC)
#define B_ 16
#define H_ 512
#define W_ 512
#define TILES (H_ / TH)      // 128
#define RS (W_ * 3)          // row stride in floats

#define EXP2(x) __builtin_amdgcn_exp2f(x)

typedef float f4 __attribute__((ext_vector_type(4), aligned(4)));
typedef float f2 __attribute__((ext_vector_type(2)));   // -> v_pk_*_f32

// 15-float row, 4 VMEM instrs (16B loads, 4B-aligned; e overlaps c.w)
__device__ __forceinline__ void load15(float d[15], const float* __restrict__ p) {
    f4 a = *(const f4*)(p + 0);
    f4 b = *(const f4*)(p + 4);
    f4 c = *(const f4*)(p + 8);
    f4 e = *(const f4*)(p + 11);
    d[0] = a.x;  d[1] = a.y;  d[2]  = a.z;  d[3]  = a.w;
    d[4] = b.x;  d[5] = b.y;  d[6]  = b.z;  d[7]  = b.w;
    d[8] = c.x;  d[9] = c.y;  d[10] = c.z;  d[11] = e.x;
    d[12] = e.y; d[13] = e.z; d[14] = e.w;
}

// channel-packed texel: {r,g} and {b, 1.0}. The 1.0 rides the y-half of the
// accumulator pk_fma so den accumulation is free.
struct Tex { f2 rg; f2 b1; };

// 5 taps of one window row (dy unroll-constant) for one center pixel,
// channel-packed: ~9 VALU issues/tap vs 12 scalar.
// Center tap (dy==2,dx==2) is pre-folded into the accumulator init.
__device__ __forceinline__ void taps_row_pk(const Tex tx[5], int dy,
                                            f2 crg, f2 cb1,
                                            f2& accrg, f2& accb1) {
    const int sdy = (dy - 2) * (dy - 2);
#pragma unroll
    for (int dx = 0; dx < 5; ++dx) {
        if (dy == 2 && dx == 2) continue;   // folds away
        f2 d01 = tx[dx].rg - crg;           // v_pk_add_f32 (neg)
        f2 d23 = tx[dx].b1 - cb1;           // y half: 1-1 = 0
        f2 s = d01 * d01;                   // v_pk_mul_f32
        s = __builtin_elementwise_fma(d23, d23, s);   // [db2+dr2, 0+dg2]
        const float cd = s.x + s.y;
        const float spatial =
            -0.5f * LOG2E * (float)(sdy + (dx - 2) * (dx - 2));
        const float w = EXP2(fmaf(cd, NEG50L, spatial));
        const f2 w2 = {w, w};
        accrg = __builtin_elementwise_fma(w2, tx[dx].rg, accrg);
        accb1 = __builtin_elementwise_fma(w2, tx[dx].b1, accb1);  // y: den+=w
    }
}

// build packed texels from a flat 15-float row (amortized over <=4 centers)
__device__ __forceinline__ void pack_row(Tex tx[5], const float row[15]) {
#pragma unroll
    for (int dx = 0; dx < 5; ++dx) {
        tx[dx].rg = (f2){row[3 * dx + 0], row[3 * dx + 1]};
        tx[dx].b1 = (f2){row[3 * dx + 2], 1.0f};
    }
}

// One thread = (batch, column, 4-row tile). Streams 8 input rows; one row
// live at a time. R2 skeleton (51.9us anchor); only tap math is packed.
__global__ __launch_bounds__(256) void bilateral_kernel(
    const float* __restrict__ x, float* __restrict__ out)
{
    const int tid = blockIdx.x * blockDim.x + threadIdx.x;
    const int wslot = tid & (W_ - 1);
    // rotate columns by +RADIUS: edge columns {0,1,510,511} all land in the
    // last 64-lane wave of each 512-column group -> 7/8 column-waves fast.
    const int w0 = (wslot + RADIUS) & (W_ - 1);
    const int t  = (tid >> 9) & (TILES - 1);
    const int b0 = tid >> 16;
    const int h0 = t * TH;

    const float* __restrict__ img = x + (size_t)b0 * (H_ * W_ * 3);
    float* __restrict__ oimg      = out + (size_t)b0 * (H_ * W_ * 3);

    const bool fast = (t >= 1) && (t <= TILES - 2) &&
                      (w0 >= RADIUS) && (w0 < W_ - RADIUS);

    // packed centers + packed accumulators (center tap w==1 pre-folded:
    // acc_rg = {cr,cg}, acc_b1 = {cb,1})
    f2 crg[TH], cb1[TH], accrg[TH], accb1[TH];

    if (__all(fast)) {
        // centers via one 16B load each (interior: always in-bounds,
        // trailing float is just the next texel's r)
#pragma unroll
        for (int j = 0; j < TH; ++j) {
            f4 c = *(const f4*)(img + ((h0 + j) * W_ + w0) * 3);
            crg[j] = (f2){c.x, c.y};
            cb1[j] = (f2){c.z, 1.0f};
            accrg[j] = crg[j];
            accb1[j] = cb1[j];
        }
        const float* p = img + ((h0 - 2) * W_ + (w0 - RADIUS)) * 3;
#pragma unroll
        for (int r = 0; r < TH + 4; ++r) {
            float row[15];
            load15(row, p);
            p += RS;
            Tex tx[5];
            pack_row(tx, row);
#pragma unroll
            for (int j = 0; j < TH; ++j) {
                if (r - j >= 0 && r - j <= 4)   // unroll-const condition
                    taps_row_pk(tx, r - j, crg[j], cb1[j], accrg[j], accb1[j]);
            }
        }
    } else {
        // boundary (~14% of waves): guarded scalar loads, same packed taps
#pragma unroll
        for (int j = 0; j < TH; ++j) {
            const float* cp = img + ((h0 + j) * W_ + w0) * 3;
            crg[j] = (f2){cp[0], cp[1]};
            cb1[j] = (f2){cp[2], 1.0f};
            accrg[j] = crg[j];
            accb1[j] = cb1[j];
        }
        bool cok[5];
#pragma unroll
        for (int jj = 0; jj < 5; ++jj) {
            const int ww = w0 - RADIUS + jj;
            cok[jj] = (ww >= 0) && (ww < W_);
        }
#pragma unroll
        for (int r = 0; r < TH + 4; ++r) {
            const int hh = h0 - 2 + r;
            const bool rowok = (hh >= 0) && (hh < H_);
            const int base = (hh * W_ + (w0 - RADIUS)) * 3;
            float row[15];
#pragma unroll
            for (int jj = 0; jj < 5; ++jj) {
                const bool ok = rowok && cok[jj];
#pragma unroll
                for (int c = 0; c < 3; ++c)
                    row[3 * jj + c] = ok ? img[base + 3 * jj + c] : 0.0f;
            }
            Tex tx[5];
            pack_row(tx, row);
#pragma unroll
            for (int j = 0; j < TH; ++j) {
                if (r - j >= 0 && r - j <= 4)
                    taps_row_pk(tx, r - j, crg[j], cb1[j], accrg[j], accb1[j]);
            }
        }
    }

#pragma unroll
    for (int j = 0; j < TH; ++j) {
        const float inv = __builtin_amdgcn_rcpf(accb1[j].y);   // den >= 1
        float* op = oimg + ((h0 + j) * W_ + w0) * 3;
        op[0] = accrg[j].x * inv;
        op[1] = accrg[j].y * inv;
        op[2] = accb1[j].x * inv;
    }
}

extern "C" void kernel_launch(void* const* d_in, const int* in_sizes, int n_in,
                              void* d_out, int out_size, void* d_ws, size_t ws_size,
                              hipStream_t stream) {
    const float* x = (const float*)d_in[0];
    float* out = (float*)d_out;

    const int total = B_ * W_ * TILES;      // 1,048,576 (exact multiple of 256)
    const int block = 256;
    const int grid = total / block;

    bilateral_kernel<<<grid, block, 0, stream>>>(x, out);
}

// Round 8
// 42.976 us; speedup vs baseline: 5.4376x; 1.2992x over previous
//
#include <hip/hip_runtime.h>

#define LOG2E 1.4426950408889634f
#define NEG50L (-50.0f * LOG2E)   // -0.5/sigma_color^2 * log2(e)

// compile-time problem shape (bench fixed at 16x512x512x3 f32 NHWC)
#define B_ 16
#define H_ 512
#define W_ 512

#define TILE_C 64            // columns per block (one lane each)
#define TH 2                 // output rows per thread  -> small live set
#define TILE_R 8             // output rows per block (4 waves x TH)
#define LR (TILE_R + 4)      // 12 LDS rows (halo'd)
#define LC (TILE_C + 4)      // 68 LDS cols (halo'd)
#define NTEX (LR * LC)       // 816 texels

#define EXP2(x) __builtin_amdgcn_exp2f(x)

typedef float f4 __attribute__((ext_vector_type(4)));              // LDS texel
typedef float f3 __attribute__((ext_vector_type(3), aligned(4))); // 12B global load

// One block = 64x8 output tile. Halo tile staged once into LDS (zero-padded
// OOB -> NO boundary path, no ballot, uniform main loop). TH=2 keeps the
// persistent live set to ~30 floats so the allocator can land <=64 VGPR:
// the untested cell {short LDS latency} x {8-wave occupancy tier}.
// (R6 = LDS @ 96 VGPR/4-wave: 56.7us. R4 = global @ 56 VGPR/8-wave but
// +50% HBM: 55.2us. R2 anchor = global @ 76 VGPR: 51.9us.)
__global__ __launch_bounds__(256) void bilateral_kernel(
    const float* __restrict__ x, float* __restrict__ out)
{
    __shared__ f4 tile[NTEX];          // 13,056 B

    const int bid = blockIdx.x;
    const int ct = bid & 7;            // 8 col tiles
    const int rt = (bid >> 3) & 63;    // 64 row tiles
    const int b0 = bid >> 9;           // 16 batches
    const int c0 = ct * TILE_C;
    const int h0 = rt * TILE_R;

    const float* __restrict__ img = x + (size_t)b0 * (H_ * W_ * 3);
    float* __restrict__ oimg      = out + (size_t)b0 * (H_ * W_ * 3);

    // ---- stage 12x68 texels; clamp address (always valid), cndmask zeros.
    // f3 (dwordx3) global loads: never read past the last valid float.
#pragma unroll
    for (int k = 0; k < 4; ++k) {
        const int s = threadIdx.x + k * 256;
        if (k < 3 || s < NTEX) {               // k<3 folds; last iter guarded
            const int lr = s / LC;
            const int lc = s - lr * LC;
            const int gr = h0 - 2 + lr;
            const int gc = c0 - 2 + lc;
            const int cr_ = min(max(gr, 0), H_ - 1);
            const int cc_ = min(max(gc, 0), W_ - 1);
            const bool ok = (gr == cr_) && (gc == cc_);
            const f3 v = *(const f3*)(img + (cr_ * W_ + cc_) * 3);
            f4 t;
            t.x = ok ? v.x : 0.0f;
            t.y = ok ? v.y : 0.0f;
            t.z = ok ? v.z : 0.0f;
            t.w = 0.0f;
            tile[s] = t;                       // ds_write_b128, dense
        }
    }
    __syncthreads();

    const int lane  = threadIdx.x & 63;        // column within tile
    const int wv    = threadIdx.x >> 6;        // wave -> 2-row group
    const int rbase = wv * TH;                 // first LDS row of my stream

    // centers: LDS row rbase+j+2, col lane+2 (tile interior, always valid)
    float cc[TH][3];
    float acc[TH][4];                          // center tap (w==1) pre-folded
#pragma unroll
    for (int j = 0; j < TH; ++j) {
        const f4 c = tile[(rbase + j + 2) * LC + (lane + 2)];
        cc[j][0] = c.x; cc[j][1] = c.y; cc[j][2] = c.z;
        acc[j][0] = c.x; acc[j][1] = c.y; acc[j][2] = c.z;
        acc[j][3] = 1.0f;
    }

    // ---- stream 6 LDS rows; each serves the windows of up to 2 centers ----
#pragma unroll
    for (int r = 0; r < TH + 4; ++r) {
        f4 row[5];
#pragma unroll
        for (int dx = 0; dx < 5; ++dx)
            row[dx] = tile[(rbase + r) * LC + (lane + dx)];

#pragma unroll
        for (int j = 0; j < TH; ++j) {
            if (r - j >= 0 && r - j <= 4) {    // unroll-const
                const int dy = r - j;
                const int sdy = (dy - 2) * (dy - 2);
                const float cr = cc[j][0], cg = cc[j][1], cb = cc[j][2];
#pragma unroll
                for (int dx = 0; dx < 5; ++dx) {
                    if (dy == 2 && dx == 2) continue;   // pre-folded center
                    const float nr = row[dx].x;
                    const float ng = row[dx].y;
                    const float nb = row[dx].z;
                    const float dr = nr - cr, dg = ng - cg, db = nb - cb;
                    float cd = dr * dr;
                    cd = fmaf(dg, dg, cd);
                    cd = fmaf(db, db, cd);
                    const float spatial =
                        -0.5f * LOG2E * (float)(sdy + (dx - 2) * (dx - 2));
                    const float w = EXP2(fmaf(cd, NEG50L, spatial));
                    acc[j][0] = fmaf(w, nr, acc[j][0]);
                    acc[j][1] = fmaf(w, ng, acc[j][1]);
                    acc[j][2] = fmaf(w, nb, acc[j][2]);
                    acc[j][3] += w;
                }
            }
        }
    }

    // ---- epilogue: all outputs in-bounds by construction ----
#pragma unroll
    for (int j = 0; j < TH; ++j) {
        const float inv = __builtin_amdgcn_rcpf(acc[j][3]);   // den >= 1
        float* op = oimg + ((size_t)(h0 + rbase + j) * W_ + (c0 + lane)) * 3;
        op[0] = acc[j][0] * inv;
        op[1] = acc[j][1] * inv;
        op[2] = acc[j][2] * inv;
    }
}

extern "C" void kernel_launch(void* const* d_in, const int* in_sizes, int n_in,
                              void* d_out, int out_size, void* d_ws, size_t ws_size,
                              hipStream_t stream) {
    const float* x = (const float*)d_in[0];
    float* out = (float*)d_out;

    const int grid = B_ * (W_ / TILE_C) * (H_ / TILE_R);   // 16*8*64 = 8192
    const int block = 256;

    bilateral_kernel<<<grid, block, 0, stream>>>(x, out);
}

// Round 9
// 39.847 us; speedup vs baseline: 5.8645x; 1.0785x over previous
//
#include <hip/hip_runtime.h>

#define LOG2E 1.4426950408889634f
#define NEG50L (-50.0f * LOG2E)   // -50/(sigma_color^2=0.01)/2 * log2(e)
#define M100L (100.0f * LOG2E)    // = -2 * NEG50L

// compile-time problem shape (bench fixed at 16x512x512x3 f32 NHWC)
#define B_ 16
#define H_ 512
#define W_ 512

#define TILE_C 64            // columns per block (one lane each)
#define TH 2                 // output rows per thread  -> small live set
#define TILE_R 8             // output rows per block (4 waves x TH)
#define LR (TILE_R + 4)      // 12 LDS rows (halo'd)
#define LC (TILE_C + 4)      // 68 LDS cols (halo'd)
#define NTEX (LR * LC)       // 816 texels

#define EXP2(x) __builtin_amdgcn_exp2f(x)

typedef float f4 __attribute__((ext_vector_type(4)));              // LDS texel
typedef float f3 __attribute__((ext_vector_type(3), aligned(4))); // 12B global load

// R8 winner (43.0us: LDS tile + 8-wave-tier live set) with one change:
// the texel's spare .w slot carries q = -50L*|rgb|^2, precomputed at staging.
// Expanding -50L*|n-c|^2 = n.w + (100L*c).n + c.w turns each tap's
// {3 sub, 3 fma} distance into {3 fma, 1 add}: 12 -> 10 issues/tap.
// Zero-padded OOB texels (q=0) remain exactly correct: arg = qc + SP.
__global__ __launch_bounds__(256) void bilateral_kernel(
    const float* __restrict__ x, float* __restrict__ out)
{
    __shared__ f4 tile[NTEX];          // 13,056 B

    const int bid = blockIdx.x;
    const int ct = bid & 7;            // 8 col tiles
    const int rt = (bid >> 3) & 63;    // 64 row tiles
    const int b0 = bid >> 9;           // 16 batches
    const int c0 = ct * TILE_C;
    const int h0 = rt * TILE_R;

    const float* __restrict__ img = x + (size_t)b0 * (H_ * W_ * 3);
    float* __restrict__ oimg      = out + (size_t)b0 * (H_ * W_ * 3);

    // ---- stage 12x68 texels; clamped address (always valid), cndmask zeros.
    // .w slot = -50L*|rgb|^2 (the quadratic-form constant for this texel).
#pragma unroll
    for (int k = 0; k < 4; ++k) {
        const int s = threadIdx.x + k * 256;
        if (k < 3 || s < NTEX) {               // k<3 folds; last iter guarded
            const int lr = s / LC;
            const int lc = s - lr * LC;
            const int gr = h0 - 2 + lr;
            const int gc = c0 - 2 + lc;
            const int cr_ = min(max(gr, 0), H_ - 1);
            const int cc_ = min(max(gc, 0), W_ - 1);
            const bool ok = (gr == cr_) && (gc == cc_);
            const f3 v = *(const f3*)(img + (cr_ * W_ + cc_) * 3);
            f4 t;
            t.x = ok ? v.x : 0.0f;
            t.y = ok ? v.y : 0.0f;
            t.z = ok ? v.z : 0.0f;
            float n2 = t.x * t.x;
            n2 = fmaf(t.y, t.y, n2);
            n2 = fmaf(t.z, t.z, n2);
            t.w = NEG50L * n2;                 // q = -50L*|n|^2 (0 for OOB)
            tile[s] = t;                       // ds_write_b128, dense
        }
    }
    __syncthreads();

    const int lane  = threadIdx.x & 63;        // column within tile
    const int wv    = threadIdx.x >> 6;        // wave -> 2-row group
    const int rbase = wv * TH;                 // first LDS row of my stream

    // per-center state: kc = 100L*c (3), qc = c.w (free from staging),
    // accumulators with center tap (w==1) pre-folded.
    float kc[TH][3], qc[TH];
    float acc[TH][4];
#pragma unroll
    for (int j = 0; j < TH; ++j) {
        const f4 c = tile[(rbase + j + 2) * LC + (lane + 2)];
        kc[j][0] = M100L * c.x;
        kc[j][1] = M100L * c.y;
        kc[j][2] = M100L * c.z;
        qc[j] = c.w;
        acc[j][0] = c.x; acc[j][1] = c.y; acc[j][2] = c.z;
        acc[j][3] = 1.0f;
    }

    // ---- stream 6 LDS rows; each serves the windows of up to 2 centers ----
#pragma unroll
    for (int r = 0; r < TH + 4; ++r) {
        f4 row[5];
#pragma unroll
        for (int dx = 0; dx < 5; ++dx)
            row[dx] = tile[(rbase + r) * LC + (lane + dx)];

#pragma unroll
        for (int j = 0; j < TH; ++j) {
            if (r - j >= 0 && r - j <= 4) {    // unroll-const
                const int dy = r - j;
                const int sdy = (dy - 2) * (dy - 2);
#pragma unroll
                for (int dx = 0; dx < 5; ++dx) {
                    if (dy == 2 && dx == 2) continue;   // pre-folded center
                    const f4 n = row[dx];
                    float s = fmaf(n.x, kc[j][0], n.w);
                    s = fmaf(n.y, kc[j][1], s);
                    s = fmaf(n.z, kc[j][2], s);
                    const float spatial =
                        -0.5f * LOG2E * (float)(sdy + (dx - 2) * (dx - 2));
                    const float arg = (s + qc[j]) + spatial;  // spatial: literal
                    const float w = EXP2(arg);
                    acc[j][0] = fmaf(w, n.x, acc[j][0]);
                    acc[j][1] = fmaf(w, n.y, acc[j][1]);
                    acc[j][2] = fmaf(w, n.z, acc[j][2]);
                    acc[j][3] += w;
                }
            }
        }
    }

    // ---- epilogue: all outputs in-bounds by construction ----
#pragma unroll
    for (int j = 0; j < TH; ++j) {
        const float inv = __builtin_amdgcn_rcpf(acc[j][3]);   // den >= 1
        float* op = oimg + ((size_t)(h0 + rbase + j) * W_ + (c0 + lane)) * 3;
        op[0] = acc[j][0] * inv;
        op[1] = acc[j][1] * inv;
        op[2] = acc[j][2] * inv;
    }
}

extern "C" void kernel_launch(void* const* d_in, const int* in_sizes, int n_in,
                              void* d_out, int out_size, void* d_ws, size_t ws_size,
                              hipStream_t stream) {
    const float* x = (const float*)d_in[0];
    float* out = (float*)d_out;

    const int grid = B_ * (W_ / TILE_C) * (H_ / TILE_R);   // 16*8*64 = 8192
    const int block = 256;

    bilateral_kernel<<<grid, block, 0, stream>>>(x, out);
}

// Round 10
// 37.783 us; speedup vs baseline: 6.1850x; 1.0546x over previous
//
#include <hip/hip_runtime.h>

#define LOG2E 1.4426950408889634f
#define NEG50L (-50.0f * LOG2E)   // -0.5/sigma_color^2 * log2(e)
#define M100L (100.0f * LOG2E)    // = -2 * NEG50L

// compile-time problem shape (bench fixed at 16x512x512x3 f32 NHWC)
#define B_ 16
#define H_ 512
#define W_ 512

#define TILE_C 64            // columns per block (one lane each)
#define TH 2                 // output rows per thread
#define TILE_R 8             // output rows per block (4 waves x TH)
#define LR (TILE_R + 4)      // 12 LDS rows (halo'd)
#define LC (TILE_C + 4)      // 68 LDS cols (halo'd)
#define NTEX (LR * LC)       // 816 texels

#define EXP2(x) __builtin_amdgcn_exp2f(x)

typedef float f4 __attribute__((ext_vector_type(4)));              // LDS texel
typedef float f3 __attribute__((ext_vector_type(3), aligned(4))); // 12B global load
typedef float f2 __attribute__((ext_vector_type(2)));             // v_pk_*_f32

// map spatial dist^2 (values 0,1,2,4,5,8) -> dense index 0..5
__device__ __forceinline__ constexpr int sidx(int sd) {
    return (sd == 0) ? 0 : (sd == 1) ? 1 : (sd == 2) ? 2
         : (sd == 4) ? 3 : (sd == 5) ? 4 : 5;
}

// R9 (39.8us) + two tap-issue cuts (we are issue-bound at ~0.67 duty;
// R8 vs R9 proved 7-wave and 9-wave tiers run identical VALUBusy):
//  1) qsp[j][6] = qc + spatial precomputed over the 6 distinct spatial
//     values -> arg is ONE add instead of two.
//  2) LDS texel = {r,g,b,1.0} with q = -50L*|rgb|^2 in a parallel scalar
//     plane -> n.xy / n.zw are ready-made even-aligned pairs for
//     v_pk_fma_f32 accumulation; the 1.0 in .w accumulates den in the
//     y-half for free. 4 acc issues -> 2.
// Tap: 3 fma + 1 add + exp + 2 pk_fma = 7-8 issues (was 10).
__global__ __launch_bounds__(256) void bilateral_kernel(
    const float* __restrict__ x, float* __restrict__ out)
{
    __shared__ f4 tile[NTEX];          // 13,056 B  {r,g,b,1}
    __shared__ float tileq[NTEX];      //  3,264 B  q = -50L*|rgb|^2 (0 if OOB)

    const int bid = blockIdx.x;
    const int ct = bid & 7;            // 8 col tiles
    const int rt = (bid >> 3) & 63;    // 64 row tiles
    const int b0 = bid >> 9;           // 16 batches
    const int c0 = ct * TILE_C;
    const int h0 = rt * TILE_R;

    const float* __restrict__ img = x + (size_t)b0 * (H_ * W_ * 3);
    float* __restrict__ oimg      = out + (size_t)b0 * (H_ * W_ * 3);

    // ---- stage 12x68 texels; clamped address (always valid), cndmask zeros.
#pragma unroll
    for (int k = 0; k < 4; ++k) {
        const int s = threadIdx.x + k * 256;
        if (k < 3 || s < NTEX) {               // k<3 folds; last iter guarded
            const int lr = s / LC;
            const int lc = s - lr * LC;
            const int gr = h0 - 2 + lr;
            const int gc = c0 - 2 + lc;
            const int cr_ = min(max(gr, 0), H_ - 1);
            const int cc_ = min(max(gc, 0), W_ - 1);
            const bool ok = (gr == cr_) && (gc == cc_);
            const f3 v = *(const f3*)(img + (cr_ * W_ + cc_) * 3);
            f4 t;
            t.x = ok ? v.x : 0.0f;
            t.y = ok ? v.y : 0.0f;
            t.z = ok ? v.z : 0.0f;
            t.w = 1.0f;                        // den rides this via pk_fma
            float n2 = t.x * t.x;
            n2 = fmaf(t.y, t.y, n2);
            n2 = fmaf(t.z, t.z, n2);
            tile[s] = t;                       // ds_write_b128
            tileq[s] = NEG50L * n2;            // ds_write_b32
        }
    }
    __syncthreads();

    const int lane  = threadIdx.x & 63;        // column within tile
    const int wv    = threadIdx.x >> 6;        // wave -> 2-row group
    const int rbase = wv * TH;                 // first LDS row of my stream

    // per-center state: kc = 100L*c (3), qsp[6] = qc + spatial table,
    // packed accumulators with center tap (w==1) pre-folded.
    float kc[TH][3], qsp[TH][6];
    f2 accRG[TH], accB1[TH];
#pragma unroll
    for (int j = 0; j < TH; ++j) {
        const int ci = (rbase + j + 2) * LC + (lane + 2);
        const f4 c = tile[ci];
        const float qc = tileq[ci];
        kc[j][0] = M100L * c.x;
        kc[j][1] = M100L * c.y;
        kc[j][2] = M100L * c.z;
        // 6 distinct spatial dist^2 values: 0,1,2,4,5,8
        qsp[j][0] = qc;
        qsp[j][1] = qc + (-0.5f * LOG2E) * 1.0f;
        qsp[j][2] = qc + (-0.5f * LOG2E) * 2.0f;
        qsp[j][3] = qc + (-0.5f * LOG2E) * 4.0f;
        qsp[j][4] = qc + (-0.5f * LOG2E) * 5.0f;
        qsp[j][5] = qc + (-0.5f * LOG2E) * 8.0f;
        accRG[j] = (f2){c.x, c.y};
        accB1[j] = (f2){c.z, 1.0f};
    }

    // ---- stream 6 LDS rows; each serves the windows of up to 2 centers ----
#pragma unroll
    for (int r = 0; r < TH + 4; ++r) {
        f4 row[5];
        float rowq[5];
#pragma unroll
        for (int dx = 0; dx < 5; ++dx) {
            const int ti = (rbase + r) * LC + (lane + dx);
            row[dx] = tile[ti];                // ds_read_b128
            rowq[dx] = tileq[ti];              // ds_read_b32 (stride-4B: free)
        }

#pragma unroll
        for (int j = 0; j < TH; ++j) {
            if (r - j >= 0 && r - j <= 4) {    // unroll-const
                const int dy = r - j;
                const int sdy = (dy - 2) * (dy - 2);
#pragma unroll
                for (int dx = 0; dx < 5; ++dx) {
                    if (dy == 2 && dx == 2) continue;   // pre-folded center
                    const f4 n = row[dx];
                    float s = fmaf(n.x, kc[j][0], rowq[dx]);
                    s = fmaf(n.y, kc[j][1], s);
                    s = fmaf(n.z, kc[j][2], s);
                    const int si = sidx(sdy + (dx - 2) * (dx - 2));
                    const float arg = s + qsp[j][si];   // compile-time si
                    const float w = EXP2(arg);
                    const f2 w2 = {w, w};               // op_sel or 1 mov
                    const f2 nRG = {n.x, n.y};          // aliases ds regs
                    const f2 nB1 = {n.z, n.w};          // {b, 1.0}
                    accRG[j] = __builtin_elementwise_fma(w2, nRG, accRG[j]);
                    accB1[j] = __builtin_elementwise_fma(w2, nB1, accB1[j]);
                }
            }
        }
    }

    // ---- epilogue: all outputs in-bounds by construction ----
#pragma unroll
    for (int j = 0; j < TH; ++j) {
        const float inv = __builtin_amdgcn_rcpf(accB1[j].y);   // den >= 1
        float* op = oimg + ((size_t)(h0 + rbase + j) * W_ + (c0 + lane)) * 3;
        op[0] = accRG[j].x * inv;
        op[1] = accRG[j].y * inv;
        op[2] = accB1[j].x * inv;
    }
}

extern "C" void kernel_launch(void* const* d_in, const int* in_sizes, int n_in,
                              void* d_out, int out_size, void* d_ws, size_t ws_size,
                              hipStream_t stream) {
    const float* x = (const float*)d_in[0];
    float* out = (float*)d_out;

    const int grid = B_ * (W_ / TILE_C) * (H_ / TILE_R);   // 16*8*64 = 8192
    const int block = 256;

    bilateral_kernel<<<grid, block, 0, stream>>>(x, out);
}